// Round 1
// baseline (687.123 us; speedup 1.0000x reference)
//
#include <hip/hip_runtime.h>
#include <hip/hip_bf16.h>

// out[b, l] = x[b, idx[l]]
// B=16384, I=4096 (row = 16 KiB), L=8192. fp32 in/out, int32 indices.
//
// Strategy: one block per row b.
//  1. Coalesced float4 load of the 16 KiB row into LDS (x read from HBM
//     exactly once -> 256 MiB total read).
//  2. Each thread reads int4 of idx (L1/L2-resident, same 32 KiB for every
//     block), gathers 4 floats from LDS, writes one coalesced float4.
// Memory-bound: 768 MiB total traffic -> ~122 us floor at 6.3 TB/s.

#define NUM_INPUTS 4096
#define NUM_LEAVES 8192

__global__ __launch_bounds__(256) void frozenInputToLeaf_gather(
    const float* __restrict__ x,
    const int* __restrict__ idx,
    float* __restrict__ out) {
    __shared__ float row[NUM_INPUTS];

    const int t = threadIdx.x;
    const int b = blockIdx.x;

    // Stage row b of x into LDS: 4096 floats = 1024 float4, 256 threads -> 4 each.
    const float4* __restrict__ xrow4 = (const float4*)(x + (size_t)b * NUM_INPUTS);
    float4* row4 = (float4*)row;
#pragma unroll
    for (int i = 0; i < 4; ++i) {
        row4[i * 256 + t] = xrow4[i * 256 + t];
    }
    __syncthreads();

    // Gather: 8192 outputs = 2048 float4, 256 threads -> 8 each (coalesced).
    const int4* __restrict__ idx4 = (const int4*)idx;
    float4* __restrict__ out4 = (float4*)(out + (size_t)b * NUM_LEAVES);
#pragma unroll
    for (int i = 0; i < 8; ++i) {
        const int v = i * 256 + t;
        const int4 id = idx4[v];
        float4 r;
        r.x = row[id.x];
        r.y = row[id.y];
        r.z = row[id.z];
        r.w = row[id.w];
        out4[v] = r;
    }
}

extern "C" void kernel_launch(void* const* d_in, const int* in_sizes, int n_in,
                              void* d_out, int out_size, void* d_ws, size_t ws_size,
                              hipStream_t stream) {
    const float* x = (const float*)d_in[0];
    const int* idx = (const int*)d_in[1];
    float* out = (float*)d_out;

    const int batch = in_sizes[0] / NUM_INPUTS;  // 16384
    frozenInputToLeaf_gather<<<batch, 256, 0, stream>>>(x, idx, out);
}